// Round 10
// baseline (142.450 us; speedup 1.0000x reference)
//
#include <hip/hip_runtime.h>
#include <hip/hip_bf16.h>
#include <stdint.h>

typedef __bf16 bf16_t;
typedef bf16_t bf16x8 __attribute__((ext_vector_type(8)));
typedef bf16_t bf16x4 __attribute__((ext_vector_type(4)));
typedef float  f32x4  __attribute__((ext_vector_type(4)));
typedef float  f32x16 __attribute__((ext_vector_type(16)));

#define E_DIM 1024
#define B_ROWS 16384

__device__ __forceinline__ void gload_lds16(const void* g, void* l) {
    __builtin_amdgcn_global_load_lds(
        (const __attribute__((address_space(1))) void*)g,
        (__attribute__((address_space(3))) void*)l,
        16, 0, 0);
}

// ---------------------------------------------------------------------------
// prep_w: [0,2048) cvt Wo_a,Wo_b -> bf16 | [2048,2560) transpose-cvt Wv
// | [2560,3072) fused bias.  (R6/R7-proven)
// ---------------------------------------------------------------------------
__global__ __launch_bounds__(256) void prep_w_k(const float* __restrict__ Wqkv_a,
                                                const float* __restrict__ bqkv_a,
                                                const float* __restrict__ Wo_a,
                                                const float* __restrict__ bo_a,
                                                const float* __restrict__ Wqkv_b,
                                                const float* __restrict__ bqkv_b,
                                                const float* __restrict__ Wo_b,
                                                const float* __restrict__ bo_b,
                                                bf16_t* __restrict__ WoB,
                                                bf16_t* __restrict__ WvT,
                                                float* __restrict__ beff) {
    const size_t MAT = (size_t)E_DIM * E_DIM;
    __shared__ float t[64][65];
    int b = blockIdx.x;
    int tid = threadIdx.x;
    if (b < 2048) {
        const int n4 = (int)(MAT / 4);
        int i = b * 256 + tid;
        const float* src = (i < n4) ? Wo_a : Wo_b;
        int j = (i < n4) ? i : i - n4;
        f32x4 v = ((const f32x4*)src)[j];
        bf16x4 o;
        o[0] = (bf16_t)v[0]; o[1] = (bf16_t)v[1];
        o[2] = (bf16_t)v[2]; o[3] = (bf16_t)v[3];
        ((bf16x4*)WoB)[i] = o;
    } else if (b < 2560) {
        int x = b - 2048;
        int ms = x >> 8;
        const float* in = (ms ? Wqkv_b : Wqkv_a) + 2 * MAT;
        bf16_t* o = WvT + (size_t)ms * MAT;
        int bb = x & 255;
        int bx = bb & 15, by = bb >> 4;
        int j0 = by * 64, k0 = bx * 64;
#pragma unroll
        for (int p = 0; p < 4; ++p) {
            int u = tid + 256 * p;
            int r = u >> 4, c4 = u & 15;
            f32x4 v = *(const f32x4*)(in + (size_t)(j0 + r) * E_DIM + k0 + c4 * 4);
            t[r][c4 * 4 + 0] = v[0]; t[r][c4 * 4 + 1] = v[1];
            t[r][c4 * 4 + 2] = v[2]; t[r][c4 * 4 + 3] = v[3];
        }
        __syncthreads();
#pragma unroll
        for (int p = 0; p < 4; ++p) {
            int u = tid + 256 * p;
            int r = u >> 4, c4 = u & 15;
            bf16x4 ov;
            ov[0] = (bf16_t)t[c4 * 4 + 0][r];
            ov[1] = (bf16_t)t[c4 * 4 + 1][r];
            ov[2] = (bf16_t)t[c4 * 4 + 2][r];
            ov[3] = (bf16_t)t[c4 * 4 + 3][r];
            *(bf16x4*)(o + (size_t)(k0 + r) * E_DIM + j0 + c4 * 4) = ov;
        }
    } else {
        int idx = (b - 2560) * 4 + (tid >> 6);
        int lane = tid & 63;
        int sel = idx >> 10;
        int i = idx & 1023;
        const float* Wo = sel ? Wo_b : Wo_a;
        const float* bv = (sel ? bqkv_b : bqkv_a) + 2 * E_DIM;
        const float* bo = sel ? bo_b : bo_a;
        float s = 0.f;
        for (int j = lane; j < E_DIM; j += 64)
            s += Wo[(size_t)i * E_DIM + j] * bv[j];
#pragma unroll
        for (int o = 32; o > 0; o >>= 1) s += __shfl_down(s, o);
        if (lane == 0) beff[sel * E_DIM + i] = s + bo[i];
    }
}

// ---------------------------------------------------------------------------
// combo: blocks [0,128)    : fuse GEMM Weff = WoB * WvT^T (bf16, R2-proven),
//                            FIRST so they overlap the cvt BW work;
//        blocks [128,2176) : X f32->bf16 convert.
// ---------------------------------------------------------------------------
__global__ __launch_bounds__(256, 2) void combo_k(const float* __restrict__ ecg,
                                                  const float* __restrict__ text,
                                                  bf16_t* __restrict__ Xb,
                                                  const bf16_t* __restrict__ WoB,
                                                  const bf16_t* __restrict__ WvT,
                                                  bf16_t* __restrict__ Weff) {
    const size_t MAT = (size_t)E_DIM * E_DIM;
    __shared__ __align__(16) bf16_t As[128][64];
    __shared__ __align__(16) bf16_t Bs[128][64];

    int b = blockIdx.x;
    int tid = threadIdx.x;

    if (b >= 128) {
        const int half = (B_ROWS * E_DIM) / 8;
        const int total = 2 * half;
        const int stride = 2048 * 256;
        for (int i = (b - 128) * 256 + tid; i < total; i += stride) {
            const float* src = (i < half) ? ecg : text;
            int j = (i < half) ? i : i - half;
            f32x4 lo = ((const f32x4*)src)[2 * j];
            f32x4 hi = ((const f32x4*)src)[2 * j + 1];
            bf16x8 v;
            v[0] = (bf16_t)lo[0]; v[1] = (bf16_t)lo[1]; v[2] = (bf16_t)lo[2]; v[3] = (bf16_t)lo[3];
            v[4] = (bf16_t)hi[0]; v[5] = (bf16_t)hi[1]; v[6] = (bf16_t)hi[2]; v[7] = (bf16_t)hi[3];
            ((bf16x8*)Xb)[i] = v;
        }
        return;
    }

    int bid = b;
    int ms = bid >> 6;
    int t  = bid & 63;
    int mt = t >> 3, nt = t & 7;
    const bf16_t* A  = WoB + (size_t)ms * MAT;
    const bf16_t* Bm = WvT + (size_t)ms * MAT;
    bf16_t*       C  = Weff + (size_t)ms * MAT;
    int m0 = mt * 128, n0 = nt * 128;

    int lane = tid & 63;
    int wid = tid >> 6;
    int wrow = (wid >> 1) * 64;
    int wcol = (wid & 1) * 64;
    int cl = lane & 15;
    int rg = lane >> 4;

    f32x4 acc[4][4] = {};

    for (int kt = 0; kt < 16; ++kt) {
#pragma unroll
        for (int i = 0; i < 4; ++i) {
            int chunk = i * 256 + wid * 64 + lane;
            int row = chunk >> 3;
            int kk8 = (chunk & 7) * 8;
            char* la = (char*)(&As[0][0]) + (size_t)(i * 256 + wid * 64) * 16;
            char* lb = (char*)(&Bs[0][0]) + (size_t)(i * 256 + wid * 64) * 16;
            gload_lds16(A  + (size_t)(m0 + row) * E_DIM + kt * 64 + kk8, la);
            gload_lds16(Bm + (size_t)(n0 + row) * E_DIM + kt * 64 + kk8, lb);
        }
        __syncthreads();
#pragma unroll
        for (int ks = 0; ks < 2; ++ks) {
            int kk = ks * 32 + rg * 8;
            bf16x8 af[4], bq[4];
#pragma unroll
            for (int m = 0; m < 4; ++m) af[m] = *(const bf16x8*)(&As[wrow + m * 16 + cl][kk]);
#pragma unroll
            for (int n = 0; n < 4; ++n) bq[n] = *(const bf16x8*)(&Bs[wcol + n * 16 + cl][kk]);
#pragma unroll
            for (int m = 0; m < 4; ++m)
#pragma unroll
                for (int n = 0; n < 4; ++n)
                    acc[m][n] = __builtin_amdgcn_mfma_f32_16x16x32_bf16(af[m], bq[n], acc[m][n], 0, 0, 0);
        }
        __syncthreads();
    }

#pragma unroll
    for (int m = 0; m < 4; ++m) {
        int r = m0 + wrow + m * 16 + rg * 4;
#pragma unroll
        for (int n = 0; n < 4; ++n) {
            int c = n0 + wcol + n * 16 + cl;
#pragma unroll
            for (int j = 0; j < 4; ++j)
                C[(size_t)(r + j) * E_DIM + c] = (bf16_t)acc[m][n][j];
        }
    }
}

// ---------------------------------------------------------------------------
// Main GEMM v3 — v2 schedule verbatim, MFMA shape switched to 32x32x16.
// 256x256 tile, BK=64, 8 waves as 4M x 2N (wave = 64 rows x 2x64 cols).
// Per wave per K-tile: frags 2m x 4n (32x32) x 4 ksteps(16) = 32 MFMA,
// 24 ds_read_b128 (8 A + 16 B) — unchanged. Phases (nh0,kh0)(nh1,kh0)
// (nh1,kh1)(nh0,kh1); stage order A0,A1,B0,B1; vmcnt(2) at q0,q3;
// XOR swizzle (frag row&7 == lane&7), setprio, XCD-swizzled grid 512.
// A/B frag: lane l -> row/col = l&31, k = (l>>5)*8 + e.
// C/D frag: col = lane&31, row = (reg&3) + 8*(reg>>2) + 4*(lane>>5).
// ---------------------------------------------------------------------------
#define VMW(n) asm volatile("s_waitcnt vmcnt(" #n ")" ::: "memory")
#define BAR()  __builtin_amdgcn_s_barrier()

__global__ __launch_bounds__(512, 2) void main_gemm_v3_k(const bf16_t* __restrict__ Xb,
                                                         const bf16_t* __restrict__ Weff,
                                                         const float* __restrict__ beff,
                                                         float* __restrict__ out) {
    const size_t MAT  = (size_t)E_DIM * E_DIM;
    const size_t XMAT = (size_t)B_ROWS * E_DIM;

    int bid = blockIdx.x;
    int wg = (bid & 7) * 64 + (bid >> 3);
    int nt = wg & 7;
    int mt = wg >> 3;
    int sel = nt >> 2;
    int n0 = (nt & 3) * 256;
    int m0 = mt * 256;

    const bf16_t* gA = Xb + (size_t)sel * XMAT + (size_t)m0 * E_DIM;
    const bf16_t* gB = Weff + (size_t)sel * MAT + (size_t)n0 * E_DIM;
    const float*  bb = beff + sel * E_DIM;

    __shared__ __align__(16) bf16_t sA[2][256 * 64];
    __shared__ __align__(16) bf16_t sB[2][256 * 64];

    int tid  = threadIdx.x;
    int lane = tid & 63;
    int wid  = tid >> 6;
    int wr = wid >> 1;          // 0..3 : 64-row group
    int wc = wid & 1;           // 0..1 : 64-col group within each B-half
    int l31 = lane & 31;
    int hi8 = (lane >> 5) * 8;  // k sub-offset
    int hi4 = (lane >> 5) * 4;  // C/D row sub-offset
    int swz = (lane & 7) << 3;

    // staging (identical to v2): chunk c -> row c>>3, col (c&7)*8 ^ (row&7)<<3
    int c0 = tid, c1 = 512 + tid;
    int r0 = c0 >> 3, r1 = c1 >> 3;
    int go0 = r0 * E_DIM + (((c0 & 7) * 8) ^ ((r0 & 7) << 3));
    int go1 = r1 * E_DIM + (((c1 & 7) * 8) ^ ((r1 & 7) << 3));
    int ld0 = c0 * 8, ld1 = c1 * 8;

    f32x16 acc[2][4] = {};
    bf16x8 af[2][2], bq[2][2];

#define STAGE_A(kt, h, prt) do { \
    gload_lds16(gA + (size_t)((h) * 128) * E_DIM + (kt) * 64 + go0, &sA[prt][(h) * 8192 + ld0]); \
    gload_lds16(gA + (size_t)((h) * 128) * E_DIM + (kt) * 64 + go1, &sA[prt][(h) * 8192 + ld1]); } while (0)
#define STAGE_B(kt, h, prt) do { \
    gload_lds16(gB + (size_t)((h) * 128) * E_DIM + (kt) * 64 + go0, &sB[prt][(h) * 8192 + ld0]); \
    gload_lds16(gB + (size_t)((h) * 128) * E_DIM + (kt) * 64 + go1, &sB[prt][(h) * 8192 + ld1]); } while (0)
#define RD_A(p, kh) do { _Pragma("unroll") for (int m = 0; m < 2; ++m) \
    _Pragma("unroll") for (int ks = 0; ks < 2; ++ks) \
    af[m][ks] = *(const bf16x8*)(&sA[p][(wr * 64 + m * 32 + l31) * 64 + (((kh) * 32 + ks * 16 + hi8) ^ swz)]); } while (0)
#define RD_B(p, nh, kh) do { _Pragma("unroll") for (int n = 0; n < 2; ++n) \
    _Pragma("unroll") for (int ks = 0; ks < 2; ++ks) \
    bq[n][ks] = *(const bf16x8*)(&sB[p][((nh) * 128 + wc * 64 + n * 32 + l31) * 64 + (((kh) * 32 + ks * 16 + hi8) ^ swz)]); } while (0)
#define MM(nh) do { __builtin_amdgcn_s_setprio(1); \
    _Pragma("unroll") for (int m = 0; m < 2; ++m) _Pragma("unroll") for (int n = 0; n < 2; ++n) { \
        acc[m][(nh) * 2 + n] = __builtin_amdgcn_mfma_f32_32x32x16_bf16(af[m][0], bq[n][0], acc[m][(nh) * 2 + n], 0, 0, 0); \
        acc[m][(nh) * 2 + n] = __builtin_amdgcn_mfma_f32_32x32x16_bf16(af[m][1], bq[n][1], acc[m][(nh) * 2 + n], 0, 0, 0); } \
    __builtin_amdgcn_s_setprio(0); } while (0)

    // prologue: tile 0 (order A0, A1, B0, B1)
    STAGE_A(0, 0, 0); STAGE_A(0, 1, 0); STAGE_B(0, 0, 0); STAGE_B(0, 1, 0);
    VMW(2);
    BAR();

#pragma unroll
    for (int t = 0; t < 16; ++t) {
        const int p = t & 1, pn = p ^ 1;
        // q0: (nh0, kh0); stage A0(t+1)
        RD_A(p, 0); RD_B(p, 0, 0);
        if (t < 15) { STAGE_A(t + 1, 0, pn); VMW(2); } else { VMW(0); }
        BAR();
        MM(0);
        BAR();
        // q1: (nh1, kh0); stage A1(t+1); A frags reused
        RD_B(p, 1, 0);
        if (t < 15) STAGE_A(t + 1, 1, pn);
        BAR();
        MM(1);
        BAR();
        // q2: (nh1, kh1); stage B0(t+1)
        RD_A(p, 1); RD_B(p, 1, 1);
        if (t < 15) STAGE_B(t + 1, 0, pn);
        BAR();
        MM(1);
        BAR();
        // q3: (nh0, kh1); stage B1(t+1); wait guards next q0
        RD_B(p, 0, 1);
        if (t < 15) { STAGE_B(t + 1, 1, pn); VMW(2); }
        BAR();
        MM(0);
        BAR();
    }

    // epilogue: +bias, f32 store (out width = 2048)
    // C/D: col = l31, row = (reg&3) + 8*(reg>>2) + 4*(lane>>5)
#pragma unroll
    for (int mi = 0; mi < 2; ++mi) {
#pragma unroll
        for (int nf = 0; nf < 4; ++nf) {
            int ch = n0 + (nf >> 1) * 128 + wc * 64 + (nf & 1) * 32 + l31;
            float bias = bb[ch];
            size_t gc = (size_t)sel * E_DIM + ch;
            int rbase = m0 + wr * 64 + mi * 32 + hi4;
#pragma unroll
            for (int g = 0; g < 4; ++g) {
#pragma unroll
                for (int j = 0; j < 4; ++j) {
                    int r = rbase + g * 8 + j;
                    out[(size_t)r * (2 * E_DIM) + gc] = acc[mi][nf][g * 4 + j] + bias;
                }
            }
        }
    }
#undef STAGE_A
#undef STAGE_B
#undef RD_A
#undef RD_B
#undef MM
}

// ---------------------------------------------------------------------------
extern "C" void kernel_launch(void* const* d_in, const int* in_sizes, int n_in,
                              void* d_out, int out_size, void* d_ws, size_t ws_size,
                              hipStream_t stream) {
    const float* text   = (const float*)d_in[0];
    const float* ecg    = (const float*)d_in[1];
    const float* Wqkv_a = (const float*)d_in[7];
    const float* bqkv_a = (const float*)d_in[8];
    const float* Wo_a   = (const float*)d_in[9];
    const float* bo_a   = (const float*)d_in[10];
    const float* Wqkv_b = (const float*)d_in[11];
    const float* bqkv_b = (const float*)d_in[12];
    const float* Wo_b   = (const float*)d_in[13];
    const float* bo_b   = (const float*)d_in[14];

    const size_t MAT  = (size_t)E_DIM * E_DIM;
    const size_t XMAT = (size_t)B_ROWS * E_DIM;
    bf16_t* WoB  = (bf16_t*)d_ws;                 // 4 MB
    bf16_t* WvT  = WoB + 2 * MAT;                 // 4 MB
    bf16_t* Weff = WvT + 2 * MAT;                 // 4 MB
    float*  beff = (float*)(Weff + 2 * MAT);      // 8 KB
    bf16_t* Xb   = (bf16_t*)(beff + 2 * E_DIM);   // 64 MB   (total ~76 MB)

    prep_w_k<<<3072, 256, 0, stream>>>(Wqkv_a, bqkv_a, Wo_a, bo_a,
                                       Wqkv_b, bqkv_b, Wo_b, bo_b,
                                       WoB, WvT, beff);
    combo_k<<<2176, 256, 0, stream>>>(ecg, text, Xb, WoB, WvT, Weff);
    main_gemm_v3_k<<<512, 512, 0, stream>>>(Xb, Weff, beff, (float*)d_out);
}

// Round 11
// 134.161 us; speedup vs baseline: 1.0618x; 1.0618x over previous
//
#include <hip/hip_runtime.h>
#include <hip/hip_bf16.h>
#include <stdint.h>

typedef __bf16 bf16_t;
typedef bf16_t bf16x8 __attribute__((ext_vector_type(8)));
typedef bf16_t bf16x4 __attribute__((ext_vector_type(4)));
typedef float  f32x4  __attribute__((ext_vector_type(4)));

#define E_DIM 1024
#define B_ROWS 16384

__device__ __forceinline__ void gload_lds16(const void* g, void* l) {
    __builtin_amdgcn_global_load_lds(
        (const __attribute__((address_space(1))) void*)g,
        (__attribute__((address_space(3))) void*)l,
        16, 0, 0);
}

// ---------------------------------------------------------------------------
// prep_w: [0,2048) cvt Wo_a,Wo_b -> bf16 | [2048,2560) transpose-cvt Wv
// | [2560,3072) fused bias.  (R6/R7/R9-proven, verbatim)
// ---------------------------------------------------------------------------
__global__ __launch_bounds__(256) void prep_w_k(const float* __restrict__ Wqkv_a,
                                                const float* __restrict__ bqkv_a,
                                                const float* __restrict__ Wo_a,
                                                const float* __restrict__ bo_a,
                                                const float* __restrict__ Wqkv_b,
                                                const float* __restrict__ bqkv_b,
                                                const float* __restrict__ Wo_b,
                                                const float* __restrict__ bo_b,
                                                bf16_t* __restrict__ WoB,
                                                bf16_t* __restrict__ WvT,
                                                float* __restrict__ beff) {
    const size_t MAT = (size_t)E_DIM * E_DIM;
    __shared__ float t[64][65];
    int b = blockIdx.x;
    int tid = threadIdx.x;
    if (b < 2048) {
        const int n4 = (int)(MAT / 4);
        int i = b * 256 + tid;
        const float* src = (i < n4) ? Wo_a : Wo_b;
        int j = (i < n4) ? i : i - n4;
        f32x4 v = ((const f32x4*)src)[j];
        bf16x4 o;
        o[0] = (bf16_t)v[0]; o[1] = (bf16_t)v[1];
        o[2] = (bf16_t)v[2]; o[3] = (bf16_t)v[3];
        ((bf16x4*)WoB)[i] = o;
    } else if (b < 2560) {
        int x = b - 2048;
        int ms = x >> 8;
        const float* in = (ms ? Wqkv_b : Wqkv_a) + 2 * MAT;
        bf16_t* o = WvT + (size_t)ms * MAT;
        int bb = x & 255;
        int bx = bb & 15, by = bb >> 4;
        int j0 = by * 64, k0 = bx * 64;
#pragma unroll
        for (int p = 0; p < 4; ++p) {
            int u = tid + 256 * p;
            int r = u >> 4, c4 = u & 15;
            f32x4 v = *(const f32x4*)(in + (size_t)(j0 + r) * E_DIM + k0 + c4 * 4);
            t[r][c4 * 4 + 0] = v[0]; t[r][c4 * 4 + 1] = v[1];
            t[r][c4 * 4 + 2] = v[2]; t[r][c4 * 4 + 3] = v[3];
        }
        __syncthreads();
#pragma unroll
        for (int p = 0; p < 4; ++p) {
            int u = tid + 256 * p;
            int r = u >> 4, c4 = u & 15;
            bf16x4 ov;
            ov[0] = (bf16_t)t[c4 * 4 + 0][r];
            ov[1] = (bf16_t)t[c4 * 4 + 1][r];
            ov[2] = (bf16_t)t[c4 * 4 + 2][r];
            ov[3] = (bf16_t)t[c4 * 4 + 3][r];
            *(bf16x4*)(o + (size_t)(k0 + r) * E_DIM + j0 + c4 * 4) = ov;
        }
    } else {
        int idx = (b - 2560) * 4 + (tid >> 6);
        int lane = tid & 63;
        int sel = idx >> 10;
        int i = idx & 1023;
        const float* Wo = sel ? Wo_b : Wo_a;
        const float* bv = (sel ? bqkv_b : bqkv_a) + 2 * E_DIM;
        const float* bo = sel ? bo_b : bo_a;
        float s = 0.f;
        for (int j = lane; j < E_DIM; j += 64)
            s += Wo[(size_t)i * E_DIM + j] * bv[j];
#pragma unroll
        for (int o = 32; o > 0; o >>= 1) s += __shfl_down(s, o);
        if (lane == 0) beff[sel * E_DIM + i] = s + bo[i];
    }
}

// ---------------------------------------------------------------------------
// combo: blocks [0,128) fuse GEMM (bf16, R2-proven, first for overlap);
//        blocks [128,2176) X f32->bf16 convert. (R9-proven, verbatim)
// ---------------------------------------------------------------------------
__global__ __launch_bounds__(256, 2) void combo_k(const float* __restrict__ ecg,
                                                  const float* __restrict__ text,
                                                  bf16_t* __restrict__ Xb,
                                                  const bf16_t* __restrict__ WoB,
                                                  const bf16_t* __restrict__ WvT,
                                                  bf16_t* __restrict__ Weff) {
    const size_t MAT = (size_t)E_DIM * E_DIM;
    __shared__ __align__(16) bf16_t As[128][64];
    __shared__ __align__(16) bf16_t Bs[128][64];

    int b = blockIdx.x;
    int tid = threadIdx.x;

    if (b >= 128) {
        const int half = (B_ROWS * E_DIM) / 8;
        const int total = 2 * half;
        const int stride = 2048 * 256;
        for (int i = (b - 128) * 256 + tid; i < total; i += stride) {
            const float* src = (i < half) ? ecg : text;
            int j = (i < half) ? i : i - half;
            f32x4 lo = ((const f32x4*)src)[2 * j];
            f32x4 hi = ((const f32x4*)src)[2 * j + 1];
            bf16x8 v;
            v[0] = (bf16_t)lo[0]; v[1] = (bf16_t)lo[1]; v[2] = (bf16_t)lo[2]; v[3] = (bf16_t)lo[3];
            v[4] = (bf16_t)hi[0]; v[5] = (bf16_t)hi[1]; v[6] = (bf16_t)hi[2]; v[7] = (bf16_t)hi[3];
            ((bf16x8*)Xb)[i] = v;
        }
        return;
    }

    int bid = b;
    int ms = bid >> 6;
    int t  = bid & 63;
    int mt = t >> 3, nt = t & 7;
    const bf16_t* A  = WoB + (size_t)ms * MAT;
    const bf16_t* Bm = WvT + (size_t)ms * MAT;
    bf16_t*       C  = Weff + (size_t)ms * MAT;
    int m0 = mt * 128, n0 = nt * 128;

    int lane = tid & 63;
    int wid = tid >> 6;
    int wrow = (wid >> 1) * 64;
    int wcol = (wid & 1) * 64;
    int cl = lane & 15;
    int rg = lane >> 4;

    f32x4 acc[4][4] = {};

    for (int kt = 0; kt < 16; ++kt) {
#pragma unroll
        for (int i = 0; i < 4; ++i) {
            int chunk = i * 256 + wid * 64 + lane;
            int row = chunk >> 3;
            int kk8 = (chunk & 7) * 8;
            char* la = (char*)(&As[0][0]) + (size_t)(i * 256 + wid * 64) * 16;
            char* lb = (char*)(&Bs[0][0]) + (size_t)(i * 256 + wid * 64) * 16;
            gload_lds16(A  + (size_t)(m0 + row) * E_DIM + kt * 64 + kk8, la);
            gload_lds16(Bm + (size_t)(n0 + row) * E_DIM + kt * 64 + kk8, lb);
        }
        __syncthreads();
#pragma unroll
        for (int ks = 0; ks < 2; ++ks) {
            int kk = ks * 32 + rg * 8;
            bf16x8 af[4], bq[4];
#pragma unroll
            for (int m = 0; m < 4; ++m) af[m] = *(const bf16x8*)(&As[wrow + m * 16 + cl][kk]);
#pragma unroll
            for (int n = 0; n < 4; ++n) bq[n] = *(const bf16x8*)(&Bs[wcol + n * 16 + cl][kk]);
#pragma unroll
            for (int m = 0; m < 4; ++m)
#pragma unroll
                for (int n = 0; n < 4; ++n)
                    acc[m][n] = __builtin_amdgcn_mfma_f32_16x16x32_bf16(af[m], bq[n], acc[m][n], 0, 0, 0);
        }
        __syncthreads();
    }

#pragma unroll
    for (int m = 0; m < 4; ++m) {
        int r = m0 + wrow + m * 16 + rg * 4;
#pragma unroll
        for (int n = 0; n < 4; ++n) {
            int c = n0 + wcol + n * 16 + cl;
#pragma unroll
            for (int j = 0; j < 4; ++j)
                C[(size_t)(r + j) * E_DIM + c] = (bf16_t)acc[m][n][j];
        }
    }
}

// ---------------------------------------------------------------------------
// Main GEMM v4 — v2 geometry (16x16x32, 256x256, BK=64, 8 waves 4Mx2N,
// 24 ds_read_b128/tile/wave, XOR swizzle) with TWO barriers per K-tile:
// per tile: {STAGE all 4 half-tiles(t+1); VMW(8); BAR; kh0: RD_A,RD_B0,MM0,
// RD_B1,MM1; kh1: same; BAR}. vmcnt(8) retires exactly tile-t's 8 loads
// (FIFO), tile-t+1's 8 stay in flight across the full compute body.
// ---------------------------------------------------------------------------
#define VMW(n) asm volatile("s_waitcnt vmcnt(" #n ")" ::: "memory")
#define BAR()  __builtin_amdgcn_s_barrier()

__global__ __launch_bounds__(512, 2) void main_gemm_v4_k(const bf16_t* __restrict__ Xb,
                                                         const bf16_t* __restrict__ Weff,
                                                         const float* __restrict__ beff,
                                                         float* __restrict__ out) {
    const size_t MAT  = (size_t)E_DIM * E_DIM;
    const size_t XMAT = (size_t)B_ROWS * E_DIM;

    int bid = blockIdx.x;
    int wg = (bid & 7) * 64 + (bid >> 3);
    int nt = wg & 7;
    int mt = wg >> 3;
    int sel = nt >> 2;
    int n0 = (nt & 3) * 256;
    int m0 = mt * 256;

    const bf16_t* gA = Xb + (size_t)sel * XMAT + (size_t)m0 * E_DIM;
    const bf16_t* gB = Weff + (size_t)sel * MAT + (size_t)n0 * E_DIM;
    const float*  bb = beff + sel * E_DIM;

    __shared__ __align__(16) bf16_t sA[2][256 * 64];
    __shared__ __align__(16) bf16_t sB[2][256 * 64];

    int tid  = threadIdx.x;
    int lane = tid & 63;
    int wid  = tid >> 6;
    int wr = wid >> 1;          // 0..3 : 64-row group
    int wc = wid & 1;           // 0..1 : 64-col group within each B-half
    int cl = lane & 15;
    int rg = lane >> 4;

    int c0 = tid, c1 = 512 + tid;
    int r0 = c0 >> 3, r1 = c1 >> 3;
    int go0 = r0 * E_DIM + (((c0 & 7) * 8) ^ ((r0 & 7) << 3));
    int go1 = r1 * E_DIM + (((c1 & 7) * 8) ^ ((r1 & 7) << 3));
    int ld0 = c0 * 8, ld1 = c1 * 8;

    int koff0 = (rg * 8) ^ ((cl & 7) << 3);
    int koff1 = (32 + rg * 8) ^ ((cl & 7) << 3);

    f32x4 acc[4][8] = {};
    bf16x8 af[4], bq[4];

#define STAGE_A(kt, h, prt) do { \
    gload_lds16(gA + (size_t)((h) * 128) * E_DIM + (kt) * 64 + go0, &sA[prt][(h) * 8192 + ld0]); \
    gload_lds16(gA + (size_t)((h) * 128) * E_DIM + (kt) * 64 + go1, &sA[prt][(h) * 8192 + ld1]); } while (0)
#define STAGE_B(kt, h, prt) do { \
    gload_lds16(gB + (size_t)((h) * 128) * E_DIM + (kt) * 64 + go0, &sB[prt][(h) * 8192 + ld0]); \
    gload_lds16(gB + (size_t)((h) * 128) * E_DIM + (kt) * 64 + go1, &sB[prt][(h) * 8192 + ld1]); } while (0)
#define RD_A(p, KOFF) do { _Pragma("unroll") for (int m = 0; m < 4; ++m) \
    af[m] = *(const bf16x8*)(&sA[p][(wr * 64 + m * 16 + cl) * 64 + (KOFF)]); } while (0)
#define RD_B(p, nh, KOFF) do { _Pragma("unroll") for (int n = 0; n < 4; ++n) \
    bq[n] = *(const bf16x8*)(&sB[p][((nh) * 128 + wc * 64 + n * 16 + cl) * 64 + (KOFF)]); } while (0)
#define MM(nh) do { __builtin_amdgcn_s_setprio(1); \
    _Pragma("unroll") for (int m = 0; m < 4; ++m) _Pragma("unroll") for (int n = 0; n < 4; ++n) \
        acc[m][(nh) * 4 + n] = __builtin_amdgcn_mfma_f32_16x16x32_bf16(af[m], bq[n], acc[m][(nh) * 4 + n], 0, 0, 0); \
    __builtin_amdgcn_s_setprio(0); } while (0)

    // prologue: stage tile 0 into buf0 (no wait needed; loop's VMW(8) covers it)
    STAGE_A(0, 0, 0); STAGE_A(0, 1, 0); STAGE_B(0, 0, 0); STAGE_B(0, 1, 0);

#pragma unroll
    for (int t = 0; t < 16; ++t) {
        const int p = t & 1, pn = p ^ 1;
        // stage the whole next tile (8 loads), then retire exactly tile t's 8
        if (t < 15) {
            STAGE_A(t + 1, 0, pn); STAGE_A(t + 1, 1, pn);
            STAGE_B(t + 1, 0, pn); STAGE_B(t + 1, 1, pn);
            VMW(8);
        } else {
            VMW(0);
        }
        BAR();
        // kh0
        RD_A(p, koff0);
        RD_B(p, 0, koff0);
        MM(0);
        RD_B(p, 1, koff0);
        MM(1);
        // kh1
        RD_A(p, koff1);
        RD_B(p, 1, koff1);
        MM(1);
        RD_B(p, 0, koff1);
        MM(0);
        BAR();   // WAR guard: all reads of buf p done before next tile stages into it
    }

    // epilogue: +bias, f32 store (out width = 2048)
#pragma unroll
    for (int m = 0; m < 4; ++m) {
        int r = m0 + wr * 64 + m * 16 + rg * 4;
#pragma unroll
        for (int ni = 0; ni < 8; ++ni) {
            int ch = n0 + (ni >> 2) * 128 + wc * 64 + (ni & 3) * 16 + cl;
            float bias = bb[ch];
            size_t gc = (size_t)sel * E_DIM + ch;
#pragma unroll
            for (int j = 0; j < 4; ++j)
                out[(size_t)(r + j) * (2 * E_DIM) + gc] = acc[m][ni][j] + bias;
        }
    }
#undef STAGE_A
#undef STAGE_B
#undef RD_A
#undef RD_B
#undef MM
}

// ---------------------------------------------------------------------------
extern "C" void kernel_launch(void* const* d_in, const int* in_sizes, int n_in,
                              void* d_out, int out_size, void* d_ws, size_t ws_size,
                              hipStream_t stream) {
    const float* text   = (const float*)d_in[0];
    const float* ecg    = (const float*)d_in[1];
    const float* Wqkv_a = (const float*)d_in[7];
    const float* bqkv_a = (const float*)d_in[8];
    const float* Wo_a   = (const float*)d_in[9];
    const float* bo_a   = (const float*)d_in[10];
    const float* Wqkv_b = (const float*)d_in[11];
    const float* bqkv_b = (const float*)d_in[12];
    const float* Wo_b   = (const float*)d_in[13];
    const float* bo_b   = (const float*)d_in[14];

    const size_t MAT  = (size_t)E_DIM * E_DIM;
    const size_t XMAT = (size_t)B_ROWS * E_DIM;
    bf16_t* WoB  = (bf16_t*)d_ws;                 // 4 MB
    bf16_t* WvT  = WoB + 2 * MAT;                 // 4 MB
    bf16_t* Weff = WvT + 2 * MAT;                 // 4 MB
    float*  beff = (float*)(Weff + 2 * MAT);      // 8 KB
    bf16_t* Xb   = (bf16_t*)(beff + 2 * E_DIM);   // 64 MB   (total ~76 MB)

    prep_w_k<<<3072, 256, 0, stream>>>(Wqkv_a, bqkv_a, Wo_a, bo_a,
                                       Wqkv_b, bqkv_b, Wo_b, bo_b,
                                       WoB, WvT, beff);
    combo_k<<<2176, 256, 0, stream>>>(ecg, text, Xb, WoB, WvT, Weff);
    main_gemm_v4_k<<<512, 512, 0, stream>>>(Xb, Weff, beff, (float*)d_out);
}